// Round 2
// baseline (266.063 us; speedup 1.0000x reference)
//
#include <hip/hip_runtime.h>
#include <hip/hip_bf16.h>

// MHA: B=2, S=2048, D=1024, H=16, dk=64.  M = B*S = 4096.
// ws layout (bytes):
//   0: Wt_q | 2MB: Wt_k | 4MB: Wt_v | 6MB: Wt_o   bf16 [out][in]
//   8MB: Q2  [M,1024] bf16 (pre-scaled by 0.125*log2e)
//  16MB: K2  [M,1024] bf16
//  24MB: Vt  [B,H,64,S] bf16 (V transposed per head)
//  32MB: ctx [M,1024] bf16
// total 40MB of d_ws.

typedef __bf16 bf16x8 __attribute__((ext_vector_type(8)));
typedef float  f32x4  __attribute__((ext_vector_type(4)));

#define DEVI __device__ __forceinline__
// XOR swizzle: 16B-chunk of a 128B row XORed with (row&7) -> conflict-free
// ds_read_b128 column access (guide §6 G4).  cb must be 16B-aligned.
#define SWZ(row, cb) ((cb) ^ (((row) & 7) << 4))

// global -> LDS direct (16B per lane, wave-uniform LDS base; guide §5)
#define GLOAD16(gsrc, ldst)                                                    \
    __builtin_amdgcn_global_load_lds(                                          \
        (const __attribute__((address_space(1))) unsigned int*)(gsrc),         \
        (__attribute__((address_space(3))) unsigned int*)(ldst), 16, 0, 0)

static DEVI unsigned short f2bf(float f) {
    __hip_bfloat16 h = __float2bfloat16(f);
    return __builtin_bit_cast(unsigned short, h);
}
static DEVI unsigned int pack2(float a, float b) {
    return (unsigned int)f2bf(a) | ((unsigned int)f2bf(b) << 16);
}
static DEVI bf16x8 ldsRead(const char* p) {
    return __builtin_bit_cast(bf16x8, *(const uint4*)p);
}

// ---------------------------------------------------------------------------
// Kernel 1: weight transpose + bf16 convert.  w[1024][1024] f32 -> wt[n][k] bf16
// ---------------------------------------------------------------------------
__global__ __launch_bounds__(256) void wtrans_kernel(
    const float* w0, const float* w1, const float* w2, const float* w3,
    unsigned short* t0, unsigned short* t1, unsigned short* t2, unsigned short* t3)
{
    __shared__ unsigned short tile[64][80];
    const int z = blockIdx.z;
    const float* w = (z == 0) ? w0 : (z == 1) ? w1 : (z == 2) ? w2 : w3;
    unsigned short* wt = (z == 0) ? t0 : (z == 1) ? t1 : (z == 2) ? t2 : t3;
    const int n0 = blockIdx.x * 64, k0 = blockIdx.y * 64;
    const int t = threadIdx.x;
#pragma unroll
    for (int i = 0; i < 4; i++) {
        int chunk = t + i * 256;
        int row = chunk >> 4, c4 = chunk & 15;
        float4 v = *(const float4*)(w + (size_t)(k0 + row) * 1024 + n0 + c4 * 4);
        tile[c4 * 4 + 0][row] = f2bf(v.x);
        tile[c4 * 4 + 1][row] = f2bf(v.y);
        tile[c4 * 4 + 2][row] = f2bf(v.z);
        tile[c4 * 4 + 3][row] = f2bf(v.w);
    }
    __syncthreads();
#pragma unroll
    for (int i = 0; i < 2; i++) {
        int idx = t + i * 256;
        int row = idx >> 3, ch = idx & 7;
        uint4 vv = *(const uint4*)(&tile[row][ch * 8]);
        *(uint4*)(wt + (size_t)(n0 + row) * 1024 + k0 + ch * 8) = vv;
    }
}

// ---------------------------------------------------------------------------
// GEMM core: 128x128 tile, BK=64, 4 waves in 2x2, each 64x64 out (acc[4][4]).
// A: [.][1024] f32 (reg-convert) or bf16 (global_load_lds).  B: bf16 [n][1024].
// LDS linear layout receives pre-swizzled source so swizzled ds_read works
// (guide rule 21 / m173 pattern).
// ---------------------------------------------------------------------------
template <bool AF32>
DEVI void gemm128_core(const char* Ab, const char* Bb, char* As, char* Bs,
                       int m0, int n0, f32x4 (&acc)[4][4])
{
    const int t = threadIdx.x, w = t >> 6, l = t & 63, l15 = l & 15, l4 = l >> 4;
    const int wr = w >> 1, wc = w & 1;
#pragma unroll
    for (int mr = 0; mr < 4; mr++)
#pragma unroll
        for (int nc = 0; nc < 4; nc++) acc[mr][nc] = f32x4{0.f, 0.f, 0.f, 0.f};

#pragma unroll 1
    for (int k0 = 0; k0 < 1024; k0 += 64) {
        __syncthreads();
        if (AF32) {
#pragma unroll
            for (int i = 0; i < 4; i++) {
                int idx = t + i * 256, row = idx >> 3, ch = idx & 7;
                const float4* gp =
                    (const float4*)(Ab + ((size_t)(m0 + row) * 1024 + k0 + ch * 8) * 4);
                float4 f0 = gp[0], f1 = gp[1];
                uint4 pk = {pack2(f0.x, f0.y), pack2(f0.z, f0.w),
                            pack2(f1.x, f1.y), pack2(f1.z, f1.w)};
                *(uint4*)(As + row * 128 + SWZ(row, ch * 16)) = pk;
            }
        } else {
#pragma unroll
            for (int j = 0; j < 4; j++) {
                int off = w * 4096 + j * 1024 + l * 16;
                int row = off >> 7, chsw = (off >> 4) & 7, ch = chsw ^ (row & 7);
                GLOAD16(Ab + ((size_t)(m0 + row) * 1024 + k0 + ch * 8) * 2,
                        As + w * 4096 + j * 1024);
            }
        }
#pragma unroll
        for (int j = 0; j < 4; j++) {
            int off = w * 4096 + j * 1024 + l * 16;
            int row = off >> 7, chsw = (off >> 4) & 7, ch = chsw ^ (row & 7);
            GLOAD16(Bb + ((size_t)(n0 + row) * 1024 + k0 + ch * 8) * 2,
                    Bs + w * 4096 + j * 1024);
        }
        __syncthreads();

        bf16x8 af[4][2], bfr[4][2];
#pragma unroll
        for (int mr = 0; mr < 4; mr++) {
            int row = wr * 64 + mr * 16 + l15;
#pragma unroll
            for (int kf = 0; kf < 2; kf++)
                af[mr][kf] = ldsRead(As + row * 128 + SWZ(row, kf * 64 + l4 * 16));
        }
#pragma unroll
        for (int nc = 0; nc < 4; nc++) {
            int row = wc * 64 + nc * 16 + l15;
#pragma unroll
            for (int kf = 0; kf < 2; kf++)
                bfr[nc][kf] = ldsRead(Bs + row * 128 + SWZ(row, kf * 64 + l4 * 16));
        }
#pragma unroll
        for (int kf = 0; kf < 2; kf++)
#pragma unroll
            for (int mr = 0; mr < 4; mr++)
#pragma unroll
                for (int nc = 0; nc < 4; nc++)
                    acc[mr][nc] = __builtin_amdgcn_mfma_f32_16x16x32_bf16(
                        af[mr][kf], bfr[nc][kf], acc[mr][nc], 0, 0, 0);
    }
}

// ---------------------------------------------------------------------------
// Kernel 2: QKV projections.  z=0: Q (scale 0.125*log2e), z=1: K,
// z=2: V transposed -> Vt[B,H,64,S].  Q/K stored flat [M][1024].
// ---------------------------------------------------------------------------
__global__ __launch_bounds__(256) void gemm_proj_kernel(
    const float* x0, const float* x1, const float* x2,
    const unsigned short* wt0, const unsigned short* wt1, const unsigned short* wt2,
    const float* b0, const float* b1, const float* b2,
    unsigned short* y0, unsigned short* y1, unsigned short* y2)
{
    __shared__ __align__(16) char As[128 * 64 * 2];
    __shared__ __align__(16) char Bs[128 * 64 * 2];
    const int z = blockIdx.z;
    const float* X = (z == 0) ? x0 : (z == 1) ? x1 : x2;
    const unsigned short* Wt = (z == 0) ? wt0 : (z == 1) ? wt1 : wt2;
    const float* bias = (z == 0) ? b0 : (z == 1) ? b1 : b2;
    unsigned short* Y = (z == 0) ? y0 : (z == 1) ? y1 : y2;
    const float scale = (z == 0) ? 0.125f * 1.44269504f : 1.0f;
    const int n0 = blockIdx.x * 128, m0 = blockIdx.y * 128;

    f32x4 acc[4][4];
    gemm128_core<true>((const char*)X, (const char*)Wt, As, Bs, m0, n0, acc);

    const int t = threadIdx.x, w = t >> 6, l = t & 63, l15 = l & 15, l4 = l >> 4;
    const int wr = w >> 1, wc = w & 1;
#pragma unroll
    for (int nc = 0; nc < 4; nc++) {
        int col = n0 + wc * 64 + nc * 16 + l15;
        float bv = bias[col];
        int h = col >> 6, d = col & 63;
#pragma unroll
        for (int mr = 0; mr < 4; mr++) {
#pragma unroll
            for (int r = 0; r < 4; r++) {
                int m = m0 + wr * 64 + mr * 16 + l4 * 4 + r;
                float v = (acc[mr][nc][r] + bv) * scale;
                if (z < 2)
                    Y[(size_t)m * 1024 + col] = f2bf(v);
                else {
                    int bb = m >> 11, s = m & 2047;
                    Y[(((size_t)((bb * 16 + h) * 64 + d)) << 11) + s] = f2bf(v);
                }
            }
        }
    }
}

// ---------------------------------------------------------------------------
// Kernel 3: flash attention (swapped QK^T: lane owns one query).
// Block: 4 waves, 64 q-rows, 32 K/V tiles of 64 keys.
// Q2/K2: [M,1024] bf16 (Q pre-scaled, log2 domain).  Vt: [B,H,64,S] bf16.
// ---------------------------------------------------------------------------
__global__ __launch_bounds__(256) void attn_kernel(
    const unsigned short* Q2, const unsigned short* K2, const unsigned short* VT,
    unsigned short* ctx)
{
    __shared__ __align__(16) char sm[32768];  // Q 8K | K 8K | V 8K | P 4x2K
    char* Qs = sm;
    char* Ks = sm + 8192;
    char* Vs = sm + 16384;
    const int t = threadIdx.x, w = t >> 6, l = t & 63, l15 = l & 15, l4 = l >> 4;
    char* Ps = sm + 24576 + w * 2048;  // 16 rows x 128B per wave
    const int q0 = blockIdx.x * 64;
    const int bh = blockIdx.y, b = bh >> 4, h = bh & 15;
    const char* Qb = (const char*)(Q2 + ((size_t)(b * 2048 + q0)) * 1024 + h * 64);
    const char* Kb = (const char*)(K2 + ((size_t)(b * 2048)) * 1024 + h * 64);
    const char* Vb = (const char*)(VT + (size_t)bh * 64 * 2048);

    // stage Q tile [64 q][64 dk] (row stride 2048B in global), swizzled
#pragma unroll
    for (int i = 0; i < 2; i++) {
        int idx = t + i * 256, row = idx >> 3, ch = idx & 7;
        uint4 vv = *(const uint4*)(Qb + (size_t)row * 2048 + ch * 16);
        *(uint4*)(Qs + row * 128 + SWZ(row, ch * 16)) = vv;
    }
    __syncthreads();
    bf16x8 qf[2];
    {
        int row = w * 16 + l15;
#pragma unroll
        for (int kf = 0; kf < 2; kf++)
            qf[kf] = ldsRead(Qs + row * 128 + SWZ(row, kf * 64 + l4 * 16));
    }

    f32x4 o[4];
#pragma unroll
    for (int c = 0; c < 4; c++) o[c] = f32x4{0.f, 0.f, 0.f, 0.f};
    float m_run = -1e30f, lsum = 0.f;

    uint4 kreg[2], vreg[2];
    // ---- staging helpers (T14 async split: load early, write after barrier)
#define LOADKV(KT)                                                                 \
    do {                                                                           \
        int kk0 = (KT) * 64;                                                       \
        _Pragma("unroll") for (int i = 0; i < 2; i++) {                            \
            int idx = t + i * 256, row = idx >> 3, ch = idx & 7;                   \
            kreg[i] = *(const uint4*)(Kb + (size_t)(kk0 + row) * 2048 + ch * 16);  \
            vreg[i] = *(const uint4*)(Vb + (size_t)row * 4096 + (size_t)kk0 * 2 + ch * 16); \
        }                                                                          \
    } while (0)
#define WRITEKV()                                                                  \
    do {                                                                           \
        _Pragma("unroll") for (int i = 0; i < 2; i++) {                            \
            int idx = t + i * 256, row = idx >> 3, ch = idx & 7;                   \
            *(uint4*)(Ks + row * 128 + SWZ(row, ch * 16)) = kreg[i];               \
            *(uint4*)(Vs + row * 128 + SWZ(row, ch * 16)) = vreg[i];               \
        }                                                                          \
    } while (0)

    LOADKV(0);
    WRITEKV();
    __syncthreads();

#pragma unroll 1
    for (int kt = 0; kt < 32; kt++) {
        if (kt + 1 < 32) LOADKV(kt + 1);  // in flight across compute

        // S^T = K·Q^T : lane = query (l15 of wave's 16), 16 keys per lane
        f32x4 sacc[4];
#pragma unroll
        for (int c = 0; c < 4; c++) sacc[c] = f32x4{0.f, 0.f, 0.f, 0.f};
#pragma unroll
        for (int cc = 0; cc < 4; cc++) {
            int row = cc * 16 + l15;
#pragma unroll
            for (int kf = 0; kf < 2; kf++) {
                bf16x8 kfrag = ldsRead(Ks + row * 128 + SWZ(row, kf * 64 + l4 * 16));
                sacc[cc] = __builtin_amdgcn_mfma_f32_16x16x32_bf16(kfrag, qf[kf], sacc[cc], 0, 0, 0);
            }
        }

        // per-lane softmax (log2 domain), keys split over l4 groups
        float a0 = fmaxf(fmaxf(sacc[0][0], sacc[0][1]), fmaxf(sacc[0][2], sacc[0][3]));
        float a1 = fmaxf(fmaxf(sacc[1][0], sacc[1][1]), fmaxf(sacc[1][2], sacc[1][3]));
        float a2 = fmaxf(fmaxf(sacc[2][0], sacc[2][1]), fmaxf(sacc[2][2], sacc[2][3]));
        float a3 = fmaxf(fmaxf(sacc[3][0], sacc[3][1]), fmaxf(sacc[3][2], sacc[3][3]));
        float mx = fmaxf(fmaxf(a0, a1), fmaxf(a2, a3));
        mx = fmaxf(mx, __shfl_xor(mx, 16));
        mx = fmaxf(mx, __shfl_xor(mx, 32));
        if (!__all(mx <= m_run + 8.0f)) {  // T13 defer-max
            float mn = fmaxf(m_run, mx);
            float alpha = exp2f(m_run - mn);
            m_run = mn;
            lsum *= alpha;
#pragma unroll
            for (int dd = 0; dd < 4; dd++)
#pragma unroll
                for (int r = 0; r < 4; r++) o[dd][r] *= alpha;
        }
        float s = 0.f;
#pragma unroll
        for (int cc = 0; cc < 4; cc++)
#pragma unroll
            for (int r = 0; r < 4; r++) {
                float p = exp2f(sacc[cc][r] - m_run);
                sacc[cc][r] = p;
                s += p;
            }
        s += __shfl_xor(s, 16);
        s += __shfl_xor(s, 32);
        lsum += s;

        // P[q=l15][key=cc*16+l4*4+r] -> Ps (bf16, swizzled), 4x ds_write_b64
#pragma unroll
        for (int cc = 0; cc < 4; cc++) {
            uint2 pk = {pack2(sacc[cc][0], sacc[cc][1]), pack2(sacc[cc][2], sacc[cc][3])};
            *(uint2*)(Ps + l15 * 128 + SWZ(l15, cc * 32 + (l4 >> 1) * 16) + (l4 & 1) * 8) = pk;
        }
        asm volatile("s_waitcnt lgkmcnt(0)" ::: "memory");
        __builtin_amdgcn_sched_barrier(0);

        // O^T += Vt·P^T : o[dd] lane = query l15, d = dd*16 + l4*4 + r
        bf16x8 pf[2];
#pragma unroll
        for (int kf = 0; kf < 2; kf++)
            pf[kf] = ldsRead(Ps + l15 * 128 + SWZ(l15, kf * 64 + l4 * 16));
#pragma unroll
        for (int dd = 0; dd < 4; dd++) {
            int row = dd * 16 + l15;
#pragma unroll
            for (int kf = 0; kf < 2; kf++) {
                bf16x8 vfrag = ldsRead(Vs + row * 128 + SWZ(row, kf * 64 + l4 * 16));
                o[dd] = __builtin_amdgcn_mfma_f32_16x16x32_bf16(vfrag, pf[kf], o[dd], 0, 0, 0);
            }
        }

        __syncthreads();               // all waves done reading Ks/Vs
        if (kt + 1 < 32) WRITEKV();    // vmcnt wait lands here, hidden latency
        __syncthreads();
    }

    float rinv = 1.0f / lsum;
    int q = q0 + w * 16 + l15;
    unsigned short* crow = ctx + ((size_t)(b * 2048 + q)) * 1024 + h * 64;
#pragma unroll
    for (int dd = 0; dd < 4; dd++) {
        uint2 pk = {pack2(o[dd][0] * rinv, o[dd][1] * rinv),
                    pack2(o[dd][2] * rinv, o[dd][3] * rinv)};
        *(uint2*)(crow + dd * 16 + l4 * 4) = pk;
    }
#undef LOADKV
#undef WRITEKV
}

// ---------------------------------------------------------------------------
// Kernel 4: output projection.  ctx bf16 @ Wt_o + b_out -> f32 d_out
// ---------------------------------------------------------------------------
__global__ __launch_bounds__(256) void gemm_out_kernel(
    const unsigned short* ctx, const unsigned short* wto, const float* bias, float* out)
{
    __shared__ __align__(16) char As[128 * 64 * 2];
    __shared__ __align__(16) char Bs[128 * 64 * 2];
    const int n0 = blockIdx.x * 128, m0 = blockIdx.y * 128;
    f32x4 acc[4][4];
    gemm128_core<false>((const char*)ctx, (const char*)wto, As, Bs, m0, n0, acc);
    const int t = threadIdx.x, w = t >> 6, l = t & 63, l15 = l & 15, l4 = l >> 4;
    const int wr = w >> 1, wc = w & 1;
#pragma unroll
    for (int nc = 0; nc < 4; nc++) {
        int col = n0 + wc * 64 + nc * 16 + l15;
        float bv = bias[col];
#pragma unroll
        for (int mr = 0; mr < 4; mr++)
#pragma unroll
            for (int r = 0; r < 4; r++) {
                int m = m0 + wr * 64 + mr * 16 + l4 * 4 + r;
                out[(size_t)m * 1024 + col] = acc[mr][nc][r] + bv;
            }
    }
}

// ---------------------------------------------------------------------------
extern "C" void kernel_launch(void* const* d_in, const int* in_sizes, int n_in,
                              void* d_out, int out_size, void* d_ws, size_t ws_size,
                              hipStream_t stream)
{
    (void)in_sizes; (void)n_in; (void)out_size; (void)ws_size;
    const float* q  = (const float*)d_in[0];
    const float* k  = (const float*)d_in[1];
    const float* v  = (const float*)d_in[2];
    const float* wq = (const float*)d_in[3];
    const float* bq = (const float*)d_in[4];
    const float* wk = (const float*)d_in[5];
    const float* bk = (const float*)d_in[6];
    const float* wv = (const float*)d_in[7];
    const float* bv = (const float*)d_in[8];
    const float* wo = (const float*)d_in[9];
    const float* bo = (const float*)d_in[10];

    char* ws = (char*)d_ws;
    const size_t MB = 1u << 20;
    unsigned short* WTq = (unsigned short*)(ws + 0 * MB);
    unsigned short* WTk = (unsigned short*)(ws + 2 * MB);
    unsigned short* WTv = (unsigned short*)(ws + 4 * MB);
    unsigned short* WTo = (unsigned short*)(ws + 6 * MB);
    unsigned short* Q2  = (unsigned short*)(ws + 8 * MB);
    unsigned short* K2  = (unsigned short*)(ws + 16 * MB);
    unsigned short* VT  = (unsigned short*)(ws + 24 * MB);
    unsigned short* CTX = (unsigned short*)(ws + 32 * MB);

    wtrans_kernel<<<dim3(16, 16, 4), 256, 0, stream>>>(wq, wk, wv, wo, WTq, WTk, WTv, WTo);
    gemm_proj_kernel<<<dim3(8, 32, 3), 256, 0, stream>>>(q, k, v, WTq, WTk, WTv,
                                                         bq, bk, bv, Q2, K2, VT);
    attn_kernel<<<dim3(32, 32), 256, 0, stream>>>(Q2, K2, VT, CTX);
    gemm_out_kernel<<<dim3(8, 32), 256, 0, stream>>>(CTX, WTo, bo, (float*)d_out);
}

// Round 3
// 181.448 us; speedup vs baseline: 1.4663x; 1.4663x over previous
//
#include <hip/hip_runtime.h>
#include <hip/hip_bf16.h>

// MHA: B=2, S=2048, D=1024, H=16, dk=64.  M = B*S = 4096.
// ws layout (bytes):
//   0: Wt_q | 2MB: Wt_k | 4MB: Wt_v | 6MB: Wt_o   bf16 [out][in]
//   8MB: Q2  [M,1024] bf16 (pre-scaled by 0.125*log2e)
//  16MB: K2  [M,1024] bf16
//  24MB: Vt  [B,H,64,S] bf16 (V transposed per head)
//  32MB: ctx [M,1024] bf16

typedef __bf16 bf16x8 __attribute__((ext_vector_type(8)));
typedef float  f32x4  __attribute__((ext_vector_type(4)));

#define DEVI __device__ __forceinline__
#define SWZ(row, cb) ((cb) ^ (((row) & 7) << 4))

#define GLOAD16(gsrc, ldst)                                                    \
    __builtin_amdgcn_global_load_lds(                                          \
        (const __attribute__((address_space(1))) unsigned int*)(gsrc),         \
        (__attribute__((address_space(3))) unsigned int*)(ldst), 16, 0, 0)

static DEVI unsigned short f2bf(float f) {
    __hip_bfloat16 h = __float2bfloat16(f);
    return __builtin_bit_cast(unsigned short, h);
}
static DEVI unsigned int pack2(float a, float b) {
    return (unsigned int)f2bf(a) | ((unsigned int)f2bf(b) << 16);
}
static DEVI bf16x8 ldsRead(const char* p) {
    return __builtin_bit_cast(bf16x8, *(const uint4*)p);
}

// ---------------------------------------------------------------------------
// Kernel 1: weight transpose + bf16 convert.  w[1024][1024] f32 -> wt[n][k]
// ---------------------------------------------------------------------------
__global__ __launch_bounds__(256) void wtrans_kernel(
    const float* w0, const float* w1, const float* w2, const float* w3,
    unsigned short* t0, unsigned short* t1, unsigned short* t2, unsigned short* t3)
{
    __shared__ unsigned short tile[64][80];
    const int z = blockIdx.z;
    const float* w = (z == 0) ? w0 : (z == 1) ? w1 : (z == 2) ? w2 : w3;
    unsigned short* wt = (z == 0) ? t0 : (z == 1) ? t1 : (z == 2) ? t2 : t3;
    const int n0 = blockIdx.x * 64, k0 = blockIdx.y * 64;
    const int t = threadIdx.x;
#pragma unroll
    for (int i = 0; i < 4; i++) {
        int chunk = t + i * 256;
        int row = chunk >> 4, c4 = chunk & 15;
        float4 v = *(const float4*)(w + (size_t)(k0 + row) * 1024 + n0 + c4 * 4);
        tile[c4 * 4 + 0][row] = f2bf(v.x);
        tile[c4 * 4 + 1][row] = f2bf(v.y);
        tile[c4 * 4 + 2][row] = f2bf(v.z);
        tile[c4 * 4 + 3][row] = f2bf(v.w);
    }
    __syncthreads();
#pragma unroll
    for (int i = 0; i < 2; i++) {
        int idx = t + i * 256;
        int row = idx >> 3, ch = idx & 7;
        uint4 vv = *(const uint4*)(&tile[row][ch * 8]);
        *(uint4*)(wt + (size_t)(n0 + row) * 1024 + k0 + ch * 8) = vv;
    }
}

// ---------------------------------------------------------------------------
// GEMM core (round-1 structure): C[128x64] tile, BK=64, 4 waves (32 rows each)
// ---------------------------------------------------------------------------
template <bool AF32>
DEVI void gemm_core(const char* Ab, const char* Bb, char* As, char* Bs,
                    int m0, int n0, f32x4 (&acc)[2][4])
{
    const int t = threadIdx.x;
    const int w = t >> 6, l = t & 63, l15 = l & 15, l4 = l >> 4;
#pragma unroll
    for (int rc = 0; rc < 2; rc++)
#pragma unroll
        for (int cc = 0; cc < 4; cc++) acc[rc][cc] = f32x4{0.f, 0.f, 0.f, 0.f};

#pragma unroll 1
    for (int k0 = 0; k0 < 1024; k0 += 64) {
        __syncthreads();
        if (AF32) {
#pragma unroll
            for (int i = 0; i < 4; i++) {
                int idx = t + i * 256, row = idx >> 3, ch = idx & 7;
                const float4* gp =
                    (const float4*)(Ab + ((size_t)(m0 + row) * 1024 + k0 + ch * 8) * 4);
                float4 f0 = gp[0], f1 = gp[1];
                uint4 pk = {pack2(f0.x, f0.y), pack2(f0.z, f0.w),
                            pack2(f1.x, f1.y), pack2(f1.z, f1.w)};
                *(uint4*)(As + row * 128 + SWZ(row, ch * 16)) = pk;
            }
        } else {
#pragma unroll
            for (int i = 0; i < 4; i++) {
                int idx = t + i * 256, row = idx >> 3, ch = idx & 7;
                uint4 v = *(const uint4*)(Ab + ((size_t)(m0 + row) * 1024 + k0 + ch * 8) * 2);
                *(uint4*)(As + row * 128 + SWZ(row, ch * 16)) = v;
            }
        }
#pragma unroll
        for (int i = 0; i < 2; i++) {
            int idx = t + i * 256, row = idx >> 3, ch = idx & 7;
            uint4 v = *(const uint4*)(Bb + ((size_t)(n0 + row) * 1024 + k0 + ch * 8) * 2);
            *(uint4*)(Bs + row * 128 + SWZ(row, ch * 16)) = v;
        }
        __syncthreads();

        bf16x8 af[2][2], bfr[4][2];
#pragma unroll
        for (int rc = 0; rc < 2; rc++)
#pragma unroll
            for (int kf = 0; kf < 2; kf++) {
                int row = w * 32 + rc * 16 + l15;
                af[rc][kf] = ldsRead(As + row * 128 + SWZ(row, kf * 64 + l4 * 16));
            }
#pragma unroll
        for (int cc = 0; cc < 4; cc++)
#pragma unroll
            for (int kf = 0; kf < 2; kf++) {
                int row = cc * 16 + l15;
                bfr[cc][kf] = ldsRead(Bs + row * 128 + SWZ(row, kf * 64 + l4 * 16));
            }
#pragma unroll
        for (int kf = 0; kf < 2; kf++)
#pragma unroll
            for (int rc = 0; rc < 2; rc++)
#pragma unroll
                for (int cc = 0; cc < 4; cc++)
                    acc[rc][cc] = __builtin_amdgcn_mfma_f32_16x16x32_bf16(
                        af[rc][kf], bfr[cc][kf], acc[rc][cc], 0, 0, 0);
    }
}

// ---------------------------------------------------------------------------
// Kernel 2: QKV projections.  z=0: Q flat (scale 0.125*log2e), z=1: K flat,
// z=2: V transposed -> Vt[B,H,64,S].
// ---------------------------------------------------------------------------
__global__ __launch_bounds__(256) void gemm_proj_kernel(
    const float* x0, const float* x1, const float* x2,
    const unsigned short* wt0, const unsigned short* wt1, const unsigned short* wt2,
    const float* b0, const float* b1, const float* b2,
    unsigned short* y0, unsigned short* y1, unsigned short* y2)
{
    __shared__ __align__(16) char As[128 * 64 * 2];
    __shared__ __align__(16) char Bs[64 * 64 * 2];
    const int z = blockIdx.z;
    const float* X = (z == 0) ? x0 : (z == 1) ? x1 : x2;
    const unsigned short* Wt = (z == 0) ? wt0 : (z == 1) ? wt1 : wt2;
    const float* bias = (z == 0) ? b0 : (z == 1) ? b1 : b2;
    unsigned short* Y = (z == 0) ? y0 : (z == 1) ? y1 : y2;
    const float scale = (z == 0) ? 0.125f * 1.44269504f : 1.0f;
    const int n0 = blockIdx.x * 64, m0 = blockIdx.y * 128;

    f32x4 acc[2][4];
    gemm_core<true>((const char*)X, (const char*)Wt, As, Bs, m0, n0, acc);

    const int t = threadIdx.x, w = t >> 6, l = t & 63, l15 = l & 15, l4 = l >> 4;
#pragma unroll
    for (int cc = 0; cc < 4; cc++) {
        int col = n0 + cc * 16 + l15;
        float bv = bias[col];
        int h = col >> 6, d = col & 63;
#pragma unroll
        for (int rc = 0; rc < 2; rc++) {
#pragma unroll
            for (int r = 0; r < 4; r++) {
                int m = m0 + w * 32 + rc * 16 + l4 * 4 + r;
                float v = (acc[rc][cc][r] + bv) * scale;
                if (z < 2)
                    Y[(size_t)m * 1024 + col] = f2bf(v);
                else {
                    int bb = m >> 11, s = m & 2047;
                    Y[(((size_t)((bb * 16 + h) * 64 + d)) << 11) + s] = f2bf(v);
                }
            }
        }
    }
}

// ---------------------------------------------------------------------------
// Kernel 3: flash attention.  Swapped QK^T (lane owns one query), log2-domain
// softmax w/ defer-max, K/V double-buffered via global_load_lds (pre-swizzled
// source, linear LDS dest), P aliased onto Q's LDS, XCD-aware work remap.
// LDS: QP 8K | K0 8K | K1 8K | V0 8K | V1 8K = 40KB -> 4 blocks/CU.
// ---------------------------------------------------------------------------
__global__ __launch_bounds__(256, 4) void attn_kernel(
    const unsigned short* Q2, const unsigned short* K2, const unsigned short* VT,
    unsigned short* ctx)
{
    __shared__ __align__(16) char sm[40960];
    char* Qs = sm;                      // aliased with P after prologue
    char* K0s = sm + 8192;
    char* K1s = sm + 16384;
    char* V0s = sm + 24576;
    char* V1s = sm + 32768;
    const int t = threadIdx.x, w = t >> 6, l = t & 63, l15 = l & 15, l4 = l >> 4;
    char* Ps = sm + w * 2048;           // wave-private 16 rows x 128B

    // XCD-aware remap: head bh's 32 q-tiles stay on one XCD (4 heads/XCD).
    const int i = blockIdx.x;
    const int xcd = i & 7, j = i >> 3;
    const int bh = xcd * 4 + (j >> 5), qblk = j & 31;
    const int b = bh >> 4, h = bh & 15;
    const int q0 = qblk * 64;
    const char* Qb = (const char*)(Q2 + ((size_t)(b * 2048 + q0)) * 1024 + h * 64);
    const char* Kb = (const char*)(K2 + ((size_t)(b * 2048)) * 1024 + h * 64);
    const char* Vb = (const char*)(VT + (size_t)bh * 64 * 2048);

    // prologue: stage Q tile [64 q][64 dk] (row stride 2048B), swizzled
#pragma unroll
    for (int ii = 0; ii < 2; ii++) {
        int idx = t + ii * 256, row = idx >> 3, ch = idx & 7;
        uint4 vv = *(const uint4*)(Qb + (size_t)row * 2048 + ch * 16);
        *(uint4*)(Qs + row * 128 + SWZ(row, ch * 16)) = vv;
    }
    __syncthreads();
    bf16x8 qf[2];
    {
        int row = w * 16 + l15;  // wave's own 2KB slice
#pragma unroll
        for (int kf = 0; kf < 2; kf++)
            qf[kf] = ldsRead(Qs + row * 128 + SWZ(row, kf * 64 + l4 * 16));
    }

    // DMA staging: per wave 2 K-gloads + 2 V-gloads (1KB each) per tile.
#define STAGE(KT, Kdst, Vdst)                                                  \
    do {                                                                       \
        int kk0 = (KT) * 64;                                                   \
        _Pragma("unroll") for (int jj = 0; jj < 2; jj++) {                     \
            int row = w * 16 + jj * 8 + (l >> 3);                              \
            int ch = (l & 7) ^ (row & 7);                                      \
            GLOAD16(Kb + (size_t)(kk0 + row) * 2048 + ch * 16,                 \
                    (Kdst) + w * 2048 + jj * 1024);                            \
            GLOAD16(Vb + (size_t)row * 4096 + (size_t)kk0 * 2 + ch * 16,       \
                    (Vdst) + w * 2048 + jj * 1024);                            \
        }                                                                      \
    } while (0)

    f32x4 o[4];
#pragma unroll
    for (int c = 0; c < 4; c++) o[c] = f32x4{0.f, 0.f, 0.f, 0.f};
    float m_run = -1e30f, lsum = 0.f;

    STAGE(0, K0s, V0s);

#pragma unroll 1
    for (int kt = 0; kt < 32; kt++) {
        char* Kc = (kt & 1) ? K1s : K0s;
        char* Vc = (kt & 1) ? V1s : V0s;
        if (kt < 31) {
            STAGE(kt + 1, (kt & 1) ? K0s : K1s, (kt & 1) ? V0s : V1s);
            asm volatile("s_waitcnt vmcnt(4)" ::: "memory");  // tile kt ready
        } else {
            asm volatile("s_waitcnt vmcnt(0)" ::: "memory");
        }
        __syncthreads();

        // S^T = K·Q^T : sacc[cc][r] = S[key=cc*16+l4*4+r][q=l15]
        f32x4 sacc[4];
#pragma unroll
        for (int c = 0; c < 4; c++) sacc[c] = f32x4{0.f, 0.f, 0.f, 0.f};
        __builtin_amdgcn_s_setprio(1);
#pragma unroll
        for (int cc = 0; cc < 4; cc++) {
            int row = cc * 16 + l15;
#pragma unroll
            for (int kf = 0; kf < 2; kf++) {
                bf16x8 kfrag = ldsRead(Kc + row * 128 + SWZ(row, kf * 64 + l4 * 16));
                sacc[cc] = __builtin_amdgcn_mfma_f32_16x16x32_bf16(kfrag, qf[kf], sacc[cc], 0, 0, 0);
            }
        }
        __builtin_amdgcn_s_setprio(0);

        // per-lane online softmax (log2 domain)
        float a0 = fmaxf(fmaxf(sacc[0][0], sacc[0][1]), fmaxf(sacc[0][2], sacc[0][3]));
        float a1 = fmaxf(fmaxf(sacc[1][0], sacc[1][1]), fmaxf(sacc[1][2], sacc[1][3]));
        float a2 = fmaxf(fmaxf(sacc[2][0], sacc[2][1]), fmaxf(sacc[2][2], sacc[2][3]));
        float a3 = fmaxf(fmaxf(sacc[3][0], sacc[3][1]), fmaxf(sacc[3][2], sacc[3][3]));
        float mx = fmaxf(fmaxf(a0, a1), fmaxf(a2, a3));
        mx = fmaxf(mx, __shfl_xor(mx, 16));
        mx = fmaxf(mx, __shfl_xor(mx, 32));
        if (!__all(mx <= m_run + 8.0f)) {  // T13 defer-max
            float mn = fmaxf(m_run, mx);
            float alpha = exp2f(m_run - mn);
            m_run = mn;
            lsum *= alpha;
#pragma unroll
            for (int dd = 0; dd < 4; dd++)
#pragma unroll
                for (int r = 0; r < 4; r++) o[dd][r] *= alpha;
        }
        float s = 0.f;
#pragma unroll
        for (int cc = 0; cc < 4; cc++)
#pragma unroll
            for (int r = 0; r < 4; r++) {
                float p = exp2f(sacc[cc][r] - m_run);
                sacc[cc][r] = p;
                s += p;
            }
        s += __shfl_xor(s, 16);
        s += __shfl_xor(s, 32);
        lsum += s;

        // P -> wave-private LDS: 8x ds_write_b32 (banks 4c+2(l4&1): 2-way max)
#pragma unroll
        for (int cc = 0; cc < 4; cc++) {
            int c = (cc * 2 + (l4 >> 1)) ^ (l15 & 7);
            char* base = Ps + l15 * 128 + c * 16 + (l4 & 1) * 8;
            *(unsigned int*)(base + 0) = pack2(sacc[cc][0], sacc[cc][1]);
            *(unsigned int*)(base + 4) = pack2(sacc[cc][2], sacc[cc][3]);
        }
        asm volatile("s_waitcnt lgkmcnt(0)" ::: "memory");
        __builtin_amdgcn_sched_barrier(0);

        // O^T += Vt·P^T : o[dd][r] = O[d=dd*16+l4*4+r][q=l15]
        bf16x8 pf[2];
#pragma unroll
        for (int kf = 0; kf < 2; kf++)
            pf[kf] = ldsRead(Ps + l15 * 128 + SWZ(l15, kf * 64 + l4 * 16));
        __builtin_amdgcn_s_setprio(1);
#pragma unroll
        for (int dd = 0; dd < 4; dd++) {
            int row = dd * 16 + l15;
#pragma unroll
            for (int kf = 0; kf < 2; kf++) {
                bf16x8 vfrag = ldsRead(Vc + row * 128 + SWZ(row, kf * 64 + l4 * 16));
                o[dd] = __builtin_amdgcn_mfma_f32_16x16x32_bf16(vfrag, pf[kf], o[dd], 0, 0, 0);
            }
        }
        __builtin_amdgcn_s_setprio(0);

        __syncthreads();  // all waves done with buf before next STAGE overwrites
    }
#undef STAGE

    float rinv = 1.0f / lsum;
    int q = q0 + w * 16 + l15;
    unsigned short* crow = ctx + ((size_t)(b * 2048 + q)) * 1024 + h * 64;
#pragma unroll
    for (int dd = 0; dd < 4; dd++) {
        uint2 pk = {pack2(o[dd][0] * rinv, o[dd][1] * rinv),
                    pack2(o[dd][2] * rinv, o[dd][3] * rinv)};
        *(uint2*)(crow + dd * 16 + l4 * 4) = pk;
    }
}

// ---------------------------------------------------------------------------
// Kernel 4: output projection.  ctx bf16 @ Wt_o + b_out -> f32 d_out
// ---------------------------------------------------------------------------
__global__ __launch_bounds__(256) void gemm_out_kernel(
    const unsigned short* ctx, const unsigned short* wto, const float* bias, float* out)
{
    __shared__ __align__(16) char As[128 * 64 * 2];
    __shared__ __align__(16) char Bs[64 * 64 * 2];
    const int n0 = blockIdx.x * 64, m0 = blockIdx.y * 128;
    f32x4 acc[2][4];
    gemm_core<false>((const char*)ctx, (const char*)wto, As, Bs, m0, n0, acc);
    const int t = threadIdx.x, w = t >> 6, l = t & 63, l15 = l & 15, l4 = l >> 4;
#pragma unroll
    for (int cc = 0; cc < 4; cc++) {
        int col = n0 + cc * 16 + l15;
        float bv = bias[col];
#pragma unroll
        for (int rc = 0; rc < 2; rc++)
#pragma unroll
            for (int r = 0; r < 4; r++) {
                int m = m0 + w * 32 + rc * 16 + l4 * 4 + r;
                out[(size_t)m * 1024 + col] = acc[rc][cc][r] + bv;
            }
    }
}

// ---------------------------------------------------------------------------
extern "C" void kernel_launch(void* const* d_in, const int* in_sizes, int n_in,
                              void* d_out, int out_size, void* d_ws, size_t ws_size,
                              hipStream_t stream)
{
    (void)in_sizes; (void)n_in; (void)out_size; (void)ws_size;
    const float* q  = (const float*)d_in[0];
    const float* k  = (const float*)d_in[1];
    const float* v  = (const float*)d_in[2];
    const float* wq = (const float*)d_in[3];
    const float* bq = (const float*)d_in[4];
    const float* wk = (const float*)d_in[5];
    const float* bk = (const float*)d_in[6];
    const float* wv = (const float*)d_in[7];
    const float* bv = (const float*)d_in[8];
    const float* wo = (const float*)d_in[9];
    const float* bo = (const float*)d_in[10];

    char* ws = (char*)d_ws;
    const size_t MB = 1u << 20;
    unsigned short* WTq = (unsigned short*)(ws + 0 * MB);
    unsigned short* WTk = (unsigned short*)(ws + 2 * MB);
    unsigned short* WTv = (unsigned short*)(ws + 4 * MB);
    unsigned short* WTo = (unsigned short*)(ws + 6 * MB);
    unsigned short* Q2  = (unsigned short*)(ws + 8 * MB);
    unsigned short* K2  = (unsigned short*)(ws + 16 * MB);
    unsigned short* VT  = (unsigned short*)(ws + 24 * MB);
    unsigned short* CTX = (unsigned short*)(ws + 32 * MB);

    wtrans_kernel<<<dim3(16, 16, 4), 256, 0, stream>>>(wq, wk, wv, wo, WTq, WTk, WTv, WTo);
    gemm_proj_kernel<<<dim3(16, 32, 3), 256, 0, stream>>>(q, k, v, WTq, WTk, WTv,
                                                          bq, bk, bv, Q2, K2, VT);
    attn_kernel<<<1024, 256, 0, stream>>>(Q2, K2, VT, CTX);
    gemm_out_kernel<<<dim3(16, 32), 256, 0, stream>>>(CTX, WTo, bo, (float*)d_out);
}